// Round 10
// baseline (1501.020 us; speedup 1.0000x reference)
//
#include <hip/hip_runtime.h>
#include <math.h>

#define Cdim   256
#define Ssp    8192      // D*H*W
#define Npts   65536
#define NCODES 1024
#define BETA   0.25f
#define MT     128       // points per GEMM block
#define NKC    48        // K-chunks of 16 (K=768 split: [zh|zh|zl] x [eh|el|eh])
#define ESCALE 8192.0f   // keep el out of f16-subnormal truncation
#define WS_NEED (65536 + (size_t)786432 * 2)

typedef _Float16 f16;
typedef f16   half8  __attribute__((ext_vector_type(8)));
typedef float f32x16 __attribute__((ext_vector_type(16)));

#define MFMA16(A, B, C) __builtin_amdgcn_mfma_f32_32x32x16_f16(A, B, C, 0, 0, 0)

// ---------------- embed norms ----------------
__global__ __launch_bounds__(256) void enorm_kernel(const float* __restrict__ embed,
                                                    float* __restrict__ enorm) {
    int j = blockIdx.x * 256 + threadIdx.x;
    if (j >= NCODES) return;
    const float4* row = reinterpret_cast<const float4*>(embed + (size_t)j * Cdim);
    float s = 0.f;
#pragma unroll 8
    for (int c4 = 0; c4 < Cdim / 4; ++c4) {
        float4 v = row[c4];
        s += v.x * v.x + v.y * v.y + v.z * v.z + v.w * v.w;
    }
    enorm[j] = s;
}

// ---------------- prep: split embed into f16 hi/lo, chunk-tiled ----------------
// Bws: [kc=48][code=1024][k'=16] f16. k = kc*16+k'; k 0..255 -> eh, 256..511 -> el,
// 512..767 -> eh. Scaled by ESCALE. (verified rounds 5-9)
__global__ __launch_bounds__(256) void prep_kernel(const float* __restrict__ embed,
                                                   f16* __restrict__ Bws) {
    int tid = blockIdx.x * 256 + threadIdx.x;
    int o4 = tid * 4;
    int kc = o4 >> 14;
    int r  = o4 & 16383;
    int j  = r >> 4;
    int k0 = r & 15;
#pragma unroll
    for (int i = 0; i < 4; ++i) {
        int k = kc * 16 + k0 + i;
        int c = k & 255;
        float ev = embed[j * 256 + c] * ESCALE;
        f16 eh = (f16)ev;
        f16 v  = (k >= 256 && k < 512) ? (f16)(ev - (float)eh) : eh;
        Bws[o4 + i] = v;
    }
}

// granule id (region boundaries 16/32 verified rounds 5-9)
#define GG(k) (((k) < 16) ? (2 * (k) + kb) : ((k) < 32) ? (2 * ((k) - 16) + kb) \
                                                        : (32 + 2 * ((k) - 32) + kb))

// ---------------- MFMA GEMM + fused argmin + loss (v6: 16 waves, 4/SIMD) ----------------
// 1024 thr / 16 waves (2 m-groups x 8 n-groups), 128 points x ALL 1024 codes in one
// pass (no jh loop). A = [zh|zl] 128KB LDS (XOR-swizzled), read-only after one
// barrier; no barriers in K-loop. B direct global->reg (L2/L1-hot), 1-deep prefetch
// (r6/r9 measured-best schedule). __launch_bounds__(1024,4) forces <=256 regs/wave
// -> 4 waves/SIMD (vs 2 in r6-r9): 2x latency-hiding TLP, same MFMA/LDS/B volumes.
__global__ __launch_bounds__(1024, 4) void vq_gemm(const float* __restrict__ z,
                                                   const f16* __restrict__ Bws,
                                                   const float* __restrict__ enorm,
                                                   float* __restrict__ out_idx,
                                                   float* __restrict__ loss_acc,
                                                   float* __restrict__ counts) {
    __shared__ __attribute__((aligned(16))) f16 As[MT * 512];   // 128 KB
    __shared__ float en_s[NCODES];                              // 4 KB
    __shared__ float znp[4 * MT];                               // 2 KB
    __shared__ float zn_s[MT];                                  // 0.5 KB
    __shared__ float redv[8 * MT];                              // 4 KB (wn) x row
    __shared__ int   redi[8 * MT];                              // 4 KB

    const int t  = threadIdx.x;
    const int l  = t & 63;
    const int w  = t >> 6;            // 0..15
    const int wm = w >> 3;            // 0..1 : rows [wm*64, +64)
    const int wn = w & 7;             // 0..7 : codes [wn*128, +128)
    const int ln = l & 31;
    const int kb = l >> 5;
    const int n0 = blockIdx.x * MT;
    const int b  = n0 >> 13;
    const int s0 = n0 & 8191;

    // ---- stage A (zh granules 0..31, zl 32..63, swizzle g^=(p&7)); 512 stagers,
    //      per-point tree identical to rounds 2/5-9 (4 quads of 64 c) ----
    if (t < 512) {
        const int p = t & 127;        // point row
        const int q = t >> 7;         // c-quad, 64 c each
        const float* zb = z + (size_t)b * ((size_t)Cdim * Ssp) + s0;
        float zsq = 0.f;
#pragma unroll
        for (int gi = 0; gi < 8; ++gi) {
            const int c0 = q * 64 + gi * 8;
            half8 hh, ll;
#pragma unroll
            for (int u = 0; u < 8; ++u) {     // c ascending -> zsq order == rounds 2/5-9
                float zv = __builtin_nontemporal_load(zb + (size_t)(c0 + u) * Ssp + p);
                zsq += zv * zv;
                f16 zh = (f16)zv;
                hh[u] = zh;
                ll[u] = (f16)(zv - (float)zh);
            }
            const int g0 = c0 >> 3;           // 0..31
            *(half8*)&As[p * 512 + 8 * (g0 ^ (p & 7))]        = hh;
            *(half8*)&As[p * 512 + 8 * ((32 + g0) ^ (p & 7))] = ll;
        }
        znp[q * MT + p] = zsq;
    }
    if (t < NCODES) en_s[t] = enorm[t];
    __syncthreads();
    if (t < MT)
        zn_s[t] = ((znp[t] + znp[MT + t]) + znp[2 * MT + t]) + znp[3 * MT + t];
    __syncthreads();

    // ---- K loop: wave (wm,wn) owns rows [wm*64,+64) x codes [wn*128,+128) ----
    f32x16 acc[2][4] = {};
    const f16* bbase = Bws + (size_t)(wn * 128 + ln) * 16 + kb * 8;

    half8 b0 = *(const half8*)(bbase);
    half8 b1 = *(const half8*)(bbase + 512);
    half8 b2 = *(const half8*)(bbase + 1024);
    half8 b3 = *(const half8*)(bbase + 1536);

    const int rowA = wm * 64 + ln;
#pragma unroll 2
    for (int kc = 0; kc < NKC; ++kc) {
        const int gg  = GG(kc);
        const int gsw = 8 * (gg ^ (ln & 7));
        half8 a0 = *(const half8*)&As[rowA * 512 + gsw];
        half8 a1 = *(const half8*)&As[(rowA + 32) * 512 + gsw];

        half8 n0r = b0, n1 = b1, n2 = b2, n3 = b3;
        if (kc + 1 < NKC) {
            const f16* src = bbase + (size_t)(kc + 1) * 16384;
            n0r = *(const half8*)(src);
            n1  = *(const half8*)(src + 512);
            n2  = *(const half8*)(src + 1024);
            n3  = *(const half8*)(src + 1536);
        }
        acc[0][0] = MFMA16(a0, b0, acc[0][0]);
        acc[1][0] = MFMA16(a1, b0, acc[1][0]);
        acc[0][1] = MFMA16(a0, b1, acc[0][1]);
        acc[1][1] = MFMA16(a1, b1, acc[1][1]);
        acc[0][2] = MFMA16(a0, b2, acc[0][2]);
        acc[1][2] = MFMA16(a1, b2, acc[1][2]);
        acc[0][3] = MFMA16(a0, b3, acc[0][3]);
        acc[1][3] = MFMA16(a1, b3, acc[1][3]);
        b0 = n0r; b1 = n1; b2 = n2; b3 = n3;
    }

    // ---- scores + per-wave argmin. C layout: col=lane&31,
    //      row=(reg&3)+8*(reg>>2)+4*(lane>>5)  (verified rounds 5-9) ----
    {
        const int h = l >> 5;
#pragma unroll
        for (int mm = 0; mm < 2; ++mm) {
#pragma unroll
            for (int rg = 0; rg < 16; ++rg) {
                const int row = wm * 64 + mm * 32 + (rg & 3) + 8 * (rg >> 2) + 4 * h;
                const float znv = zn_s[row];
                float bv = 3.0e38f; int bi = 0;
#pragma unroll
                for (int nn = 0; nn < 4; ++nn) {
                    const int col = wn * 128 + nn * 32 + ln;
                    float k1 = znv + en_s[col];
                    float sc = k1 - acc[mm][nn][rg] * (2.0f / ESCALE);
                    if (sc < bv) { bv = sc; bi = col; }
                }
#pragma unroll
                for (int off = 1; off < 32; off <<= 1) {
                    float ov = __shfl_xor(bv, off, 64);
                    int   oi = __shfl_xor(bi, off, 64);
                    if (ov < bv || (ov == bv && oi < bi)) { bv = ov; bi = oi; }
                }
                if (ln == 0) {
                    redv[wn * MT + row] = bv;
                    redi[wn * MT + row] = bi;
                }
            }
        }
    }
    __syncthreads();

    // ---- final argmin (wn ascending = col ascending); index/count; loss ----
    if (t < MT) {
        float bv = redv[t]; int bi = redi[t];
#pragma unroll
        for (int s = 1; s < 8; ++s) {
            float ov = redv[s * MT + t]; int oi = redi[s * MT + t];
            if (ov < bv || (ov == bv && oi < bi)) { bv = ov; bi = oi; }
        }
        out_idx[n0 + t] = (float)bi;
        atomicAdd(&counts[bi], 1.0f);
        float lsum = bv;
#pragma unroll
        for (int off = 32; off > 0; off >>= 1) lsum += __shfl_down(lsum, off, 64);
        if ((t & 63) == 0) atomicAdd(loss_acc, lsum);
    }
}

// ---------------- epilogue: z_q gather-write only (no z read, no loss) ----------------
__global__ __launch_bounds__(256) void vq_epi(const float* __restrict__ embed,
                                              const float* __restrict__ out_idx,
                                              float* __restrict__ out_zq) {
    const int n = blockIdx.x * 256 + threadIdx.x;
    const int b = n >> 13, s = n & 8191;
    const int idx = (int)out_idx[n];
    const float4* er = reinterpret_cast<const float4*>(embed + (size_t)idx * Cdim);
    float* oq = out_zq + (size_t)b * ((size_t)Cdim * Ssp) + s;
#pragma unroll 4
    for (int c4 = 0; c4 < Cdim / 4; ++c4) {
        float4 e = er[c4];                   // per-lane gather, L2-hot (embed = 1MB)
        const int c = c4 * 4;
        __builtin_nontemporal_store(e.x, oq + (size_t)(c + 0) * Ssp);
        __builtin_nontemporal_store(e.y, oq + (size_t)(c + 1) * Ssp);
        __builtin_nontemporal_store(e.z, oq + (size_t)(c + 2) * Ssp);
        __builtin_nontemporal_store(e.w, oq + (size_t)(c + 3) * Ssp);
    }
}

// ================= fallback (round-4 verified kernel, used if ws too small) =================
#define PTS 64
#define CT  128
#define KC  32
__global__ __launch_bounds__(256, 2) void vq_main_fb(const float* __restrict__ z,
                                                     const float* __restrict__ embed,
                                                     const float* __restrict__ enorm,
                                                     float* __restrict__ out_zq,
                                                     float* __restrict__ out_idx,
                                                     float* __restrict__ loss_acc,
                                                     float* __restrict__ counts) {
    __shared__ __attribute__((aligned(16))) float smem[Cdim * PTS + KC * CT];
    float* zt = smem;
    float* et = smem + Cdim * PTS;
    const int t  = threadIdx.x;
    const int n0 = blockIdx.x * PTS;
    const int b  = n0 >> 13;
    const int s0 = n0 & 8191;
    const float* zb = z + (size_t)b * Cdim * Ssp + s0;
    {
        const int p4 = (t & 15) * 4, crow = t >> 4;
#pragma unroll
        for (int it = 0; it < 16; ++it) {
            int c = it * 16 + crow;
            float4 v = *reinterpret_cast<const float4*>(zb + (size_t)c * Ssp + p4);
            *reinterpret_cast<float4*>(&zt[c * PTS + p4]) = v;
        }
    }
    __syncthreads();
    {
        const int p = t & 63, qq = t >> 6;
        float sacc = 0.f;
#pragma unroll 8
        for (int c = qq * 64; c < qq * 64 + 64; ++c) { float v = zt[c * PTS + p]; sacc += v * v; }
        et[qq * 64 + p] = sacc;
    }
    __syncthreads();
    const int pg = t & 15, jg = t >> 4;
    const int p0 = pg * 4;
    float zn[4];
#pragma unroll
    for (int i = 0; i < 4; ++i) {
        int p = p0 + i;
        zn[i] = ((et[p] + et[64 + p]) + et[128 + p]) + et[192 + p];
    }
    float bestv[4] = {3.0e38f, 3.0e38f, 3.0e38f, 3.0e38f};
    int   besti[4] = {0, 0, 0, 0};
    const int dj = t >> 3, q = t & 7;
    const int sw_st = (q & 3) << 3;
    for (int jt = 0; jt < NCODES / CT; ++jt) {
        const int J0 = jt * CT;
        float acc[4][8];
#pragma unroll
        for (int i = 0; i < 4; ++i)
#pragma unroll
            for (int m = 0; m < 8; ++m) acc[i][m] = 0.f;
        for (int ks = 0; ks < Cdim / KC; ++ks) {
            const int cc0 = ks * KC;
            __syncthreads();
#pragma unroll
            for (int i = 0; i < 4; ++i) {
                const int jrel = dj + 32 * i;
                const float4 v = *reinterpret_cast<const float4*>(
                    embed + (size_t)(J0 + jrel) * Cdim + cc0 + q * 4);
                const int c0 = q * 4;
                const int jsw = jrel ^ sw_st;
                et[(c0 + 0) * CT + jsw] = v.x;
                et[(c0 + 1) * CT + jsw] = v.y;
                et[(c0 + 2) * CT + jsw] = v.z;
                et[(c0 + 3) * CT + jsw] = v.w;
            }
            __syncthreads();
#pragma unroll 4
            for (int c = 0; c < KC; ++c) {
                const float4 zp = *reinterpret_cast<const float4*>(&zt[(cc0 + c) * PTS + p0]);
                const int jb = (jg * 8) ^ (((c >> 2) & 3) << 3);
                const float4 ea = *reinterpret_cast<const float4*>(&et[c * CT + jb]);
                const float4 eb = *reinterpret_cast<const float4*>(&et[c * CT + jb + 4]);
                const float zc[4] = {zp.x, zp.y, zp.z, zp.w};
                const float ec[8] = {ea.x, ea.y, ea.z, ea.w, eb.x, eb.y, eb.z, eb.w};
#pragma unroll
                for (int i = 0; i < 4; ++i)
#pragma unroll
                    for (int m = 0; m < 8; ++m) acc[i][m] += zc[i] * ec[m];
            }
        }
#pragma unroll
        for (int m = 0; m < 8; ++m) {
            const int cid = J0 + jg * 8 + m;
            const float en = enorm[cid];
#pragma unroll
            for (int i = 0; i < 4; ++i) {
                float k1 = zn[i] + en;
                float sc = k1 - 2.0f * acc[i][m];
                if (sc < bestv[i]) { bestv[i] = sc; besti[i] = cid; }
            }
        }
    }
    __syncthreads();
    float* rv = et; int* ri = (int*)(et + 1024); int* idxf = (int*)(et + 2048);
#pragma unroll
    for (int i = 0; i < 4; ++i) { int p = p0 + i; rv[p * 16 + jg] = bestv[i]; ri[p * 16 + jg] = besti[i]; }
    __syncthreads();
    if (t < PTS) {
        int p = t;
        float bv = rv[p * 16]; int bi = ri[p * 16];
        for (int g = 1; g < 16; ++g) {
            float v = rv[p * 16 + g]; int ii = ri[p * 16 + g];
            if (v < bv || (v == bv && ii < bi)) { bv = v; bi = ii; }
        }
        idxf[p] = bi;
        out_idx[n0 + p] = (float)bi;
        atomicAdd(&counts[bi], 1.0f);
    }
    __syncthreads();
    float lsum = 0.f;
    {
        const int p = t & 63, cbase = t >> 6;
        const int myidx = idxf[p];
        const float4* erow4 = reinterpret_cast<const float4*>(embed + (size_t)myidx * Cdim);
        float* ob = out_zq + (size_t)b * Cdim * Ssp + s0 + p;
#pragma unroll 4
        for (int pass = 0; pass < 16; ++pass) {
            int c = cbase * 64 + pass * 4;
            float4 e = erow4[c >> 2];
            ob[(size_t)(c + 0) * Ssp] = e.x;
            ob[(size_t)(c + 1) * Ssp] = e.y;
            ob[(size_t)(c + 2) * Ssp] = e.z;
            ob[(size_t)(c + 3) * Ssp] = e.w;
            float d0 = zt[(c + 0) * PTS + p] - e.x;
            float d1 = zt[(c + 1) * PTS + p] - e.y;
            float d2 = zt[(c + 2) * PTS + p] - e.z;
            float d3 = zt[(c + 3) * PTS + p] - e.w;
            lsum += d0 * d0 + d1 * d1 + d2 * d2 + d3 * d3;
        }
    }
#pragma unroll
    for (int off = 32; off > 0; off >>= 1) lsum += __shfl_down(lsum, off, 64);
    if ((t & 63) == 0) atomicAdd(loss_acc, lsum);
}

// ---------------- finalize ----------------
__global__ __launch_bounds__(1024) void vq_final(const float* __restrict__ counts,
                                                 const float* __restrict__ loss_acc,
                                                 float* __restrict__ out_loss,
                                                 float* __restrict__ out_perp) {
    __shared__ float red[16];
    int t = threadIdx.x;
    float cnt = counts[t];
    float avg = cnt * (1.0f / (float)Npts);
    float term = avg * logf(avg + 1e-10f);
#pragma unroll
    for (int off = 32; off > 0; off >>= 1) term += __shfl_down(term, off, 64);
    if ((t & 63) == 0) red[t >> 6] = term;
    __syncthreads();
    if (t == 0) {
        float s = 0.f;
        for (int i = 0; i < 16; ++i) s += red[i];
        *out_perp = expf(-s);
        *out_loss = BETA * loss_acc[0] * (1.0f / 16777216.0f);
    }
}

extern "C" void kernel_launch(void* const* d_in, const int* in_sizes, int n_in,
                              void* d_out, int out_size, void* d_ws, size_t ws_size,
                              hipStream_t stream) {
    const float* z     = (const float*)d_in[0];
    const float* embed = (const float*)d_in[1];

    float* ws       = (float*)d_ws;
    float* loss_acc = ws;            // [0]
    float* counts   = ws + 64;       // [1024]
    float* enorm    = ws + 2048;     // [1024]

    float* out_zq   = (float*)d_out;
    float* out_idx  = out_zq + (size_t)Npts * Cdim;
    float* out_loss = out_idx + Npts;
    float* out_perp = out_loss + 1;

    hipMemsetAsync(d_ws, 0, 2048 * sizeof(float), stream);
    enorm_kernel<<<NCODES / 256, 256, 0, stream>>>(embed, enorm);

    if (ws_size >= WS_NEED) {
        f16* Bws = (f16*)((char*)d_ws + 65536);
        prep_kernel<<<768, 256, 0, stream>>>(embed, Bws);
        vq_gemm<<<Npts / MT, 1024, 0, stream>>>(z, Bws, enorm, out_idx,
                                                loss_acc, counts);
        vq_epi<<<Npts / 256, 256, 0, stream>>>(embed, out_idx, out_zq);
    } else {
        vq_main_fb<<<Npts / PTS, 256, 0, stream>>>(z, embed, enorm, out_zq, out_idx,
                                                   loss_acc, counts);
    }
    vq_final<<<1, 1024, 0, stream>>>(counts, loss_acc, out_loss, out_perp);
}

// Round 11
// 246.293 us; speedup vs baseline: 6.0945x; 6.0945x over previous
//
#include <hip/hip_runtime.h>
#include <math.h>

#define Cdim   256
#define Ssp    8192      // D*H*W
#define Npts   65536
#define NCODES 1024
#define BETA   0.25f
#define MT     64        // points per GEMM block
#define NKC    48        // K-chunks of 16 (K=768 split: [zh|zh|zl] x [eh|el|eh])
#define ESCALE 8192.0f   // keep el out of f16-subnormal truncation
#define WS_NEED (65536 + (size_t)786432 * 2)

typedef _Float16 f16;
typedef f16   half8  __attribute__((ext_vector_type(8)));
typedef float f32x16 __attribute__((ext_vector_type(16)));

#define MFMA16(A, B, C) __builtin_amdgcn_mfma_f32_32x32x16_f16(A, B, C, 0, 0, 0)

// ---------------- embed norms ----------------
__global__ __launch_bounds__(256) void enorm_kernel(const float* __restrict__ embed,
                                                    float* __restrict__ enorm) {
    int j = blockIdx.x * 256 + threadIdx.x;
    if (j >= NCODES) return;
    const float4* row = reinterpret_cast<const float4*>(embed + (size_t)j * Cdim);
    float s = 0.f;
#pragma unroll 8
    for (int c4 = 0; c4 < Cdim / 4; ++c4) {
        float4 v = row[c4];
        s += v.x * v.x + v.y * v.y + v.z * v.z + v.w * v.w;
    }
    enorm[j] = s;
}

// ---------------- prep: split embed into f16 hi/lo, chunk-tiled ----------------
// Bws: [kc=48][code=1024][k'=16] f16. k = kc*16+k'; k 0..255 -> eh, 256..511 -> el,
// 512..767 -> eh. Scaled by ESCALE. (verified rounds 5-10)
__global__ __launch_bounds__(256) void prep_kernel(const float* __restrict__ embed,
                                                   f16* __restrict__ Bws) {
    int tid = blockIdx.x * 256 + threadIdx.x;
    int o4 = tid * 4;
    int kc = o4 >> 14;
    int r  = o4 & 16383;
    int j  = r >> 4;
    int k0 = r & 15;
#pragma unroll
    for (int i = 0; i < 4; ++i) {
        int k = kc * 16 + k0 + i;
        int c = k & 255;
        float ev = embed[j * 256 + c] * ESCALE;
        f16 eh = (f16)ev;
        f16 v  = (k >= 256 && k < 512) ? (f16)(ev - (float)eh) : eh;
        Bws[o4 + i] = v;
    }
}

// granule id (region boundaries 16/32 verified rounds 5-10)
#define GG(k) (((k) < 16) ? (2 * (k) + kb) : ((k) < 32) ? (2 * ((k) - 16) + kb) \
                                                        : (32 + 2 * ((k) - 32) + kb))

// ---------------- MFMA GEMM + fused argmin + loss (v7: LDS-B double buffer) ----------------
// 512 thr / 8 waves, 64 points x ALL 1024 codes. A = [zh|zl] 64KB LDS (r6 staging,
// verbatim). B chunk (32KB = 1024 codes x 16k) DMA'd via global_load_lds into a
// double-buffered LDS tile: one barrier per chunk, DMA of chunk k+1 overlaps
// compute of chunk k. B LDS uses a 16B-granule XOR swizzle (byte ^= ((j>>2)&3)<<4)
// for even bank spread on ds_read_b128; since global_load_lds writes linearly,
// the GLOBAL SOURCE is inverse-swizzled (rule: swizzle both sides via source).
// Wave w owns codes [w*128,+128) x all 64 rows: acc[2][4] = 128 regs.
__global__ __launch_bounds__(512, 2) void vq_gemm(const float* __restrict__ z,
                                                  const f16* __restrict__ Bws,
                                                  const float* __restrict__ enorm,
                                                  float* __restrict__ out_idx,
                                                  float* __restrict__ loss_acc,
                                                  float* __restrict__ counts) {
    __shared__ __attribute__((aligned(16))) f16 As[MT * 512];       // 64 KB
    __shared__ __attribute__((aligned(16))) f16 Bt[2][NCODES * 16]; // 64 KB
    __shared__ float en_s[NCODES];                                  // 4 KB
    __shared__ float znp[256];
    __shared__ float zn_s[MT];
    __shared__ float redv[8 * MT];
    __shared__ int   redi[8 * MT];

    const int t  = threadIdx.x;
    const int l  = t & 63;
    const int w  = t >> 6;            // 0..7 : codes [w*128, +128)
    const int ln = l & 31;
    const int kb = l >> 5;
    const int n0 = blockIdx.x * MT;
    const int b  = n0 >> 13;
    const int s0 = n0 & 8191;

    // ---- per-thread DMA source offsets (inverse of the B LDS swizzle) ----
    // slot s (16B) at LDS byte o=s*16 must hold (j,kb') with
    // S(j,kb') = (j*32 + kb'*16) ^ (((j>>2)&3)<<4) == o.
    int srcel[4];
#pragma unroll
    for (int i = 0; i < 4; ++i) {
        const int s   = i * 512 + t;
        const int o   = s * 16;
        const int jq  = o >> 7;                 // j>>2 (untouched by swizzle)
        const int lin = o ^ ((jq & 3) << 4);
        const int j   = lin >> 5;
        const int kb2 = (lin >> 4) & 1;
        srcel[i] = j * 16 + kb2 * 8;            // f16 offset within a chunk
    }

#define STAGEB(kcn, bufi)                                                          \
    {                                                                              \
        const f16* srcb = Bws + (size_t)(kcn) * 16384;                             \
        _Pragma("unroll")                                                          \
        for (int i = 0; i < 4; ++i) {                                              \
            __builtin_amdgcn_global_load_lds(                                      \
                (const __attribute__((address_space(1))) unsigned int*)(srcb + srcel[i]), \
                (__attribute__((address_space(3))) unsigned int*)&Bt[(bufi)][(size_t)(i * 512 + t) * 8], \
                16, 0, 0);                                                         \
        }                                                                          \
    }

    // ---- issue DMA for chunk 0 early (overlaps A staging below) ----
    STAGEB(0, 0)

    // ---- stage A (r6 verbatim: zh granules 0..31, zl 32..63, g^=(p&7); nt loads) ----
    if (t < 256) {
        const int p = t & 63;
        const int q = t >> 6;                 // c-quad, 64 c each
        const float* zb = z + (size_t)b * ((size_t)Cdim * Ssp) + s0;
        float zsq = 0.f;
#pragma unroll
        for (int gi = 0; gi < 8; ++gi) {
            const int c0 = q * 64 + gi * 8;
            half8 hh, ll;
#pragma unroll
            for (int u = 0; u < 8; ++u) {     // c ascending -> zsq order == rounds 2/5-10
                float zv = __builtin_nontemporal_load(zb + (size_t)(c0 + u) * Ssp + p);
                zsq += zv * zv;
                f16 zh = (f16)zv;
                hh[u] = zh;
                ll[u] = (f16)(zv - (float)zh);
            }
            const int g0 = c0 >> 3;           // 0..31
            *(half8*)&As[p * 512 + 8 * (g0 ^ (p & 7))]        = hh;
            *(half8*)&As[p * 512 + 8 * ((32 + g0) ^ (p & 7))] = ll;
        }
        znp[q * 64 + p] = zsq;
    }
    for (int i = t; i < NCODES; i += 512) en_s[i] = enorm[i];
    __syncthreads();   // drains vmcnt (DMA chunk 0 + A loads) and lgkm
    if (t < MT) zn_s[t] = ((znp[t] + znp[64 + t]) + znp[128 + t]) + znp[192 + t];

    // ---- lane's B read byte-base (swizzled); per nn: +1024 bytes ----
    const int jlane  = w * 128 + ln;
    const int bbyte0 = (jlane * 32 + kb * 16) ^ (((jlane >> 2) & 3) << 4);
    __syncthreads();

    // ---- K loop: 1 barrier per chunk; DMA(k+1) overlaps compute(k) ----
    f32x16 acc[2][4] = {};
#pragma unroll 1
    for (int kc = 0; kc < NKC; ++kc) {
        const int cur = kc & 1;
        if (kc + 1 < NKC) STAGEB(kc + 1, cur ^ 1)

        const int gg  = GG(kc);
        const int gsw = 8 * (gg ^ (ln & 7));
        half8 a0 = *(const half8*)&As[ln * 512 + gsw];
        half8 a1 = *(const half8*)&As[(32 + ln) * 512 + gsw];
        const char* bbuf = (const char*)&Bt[cur][0];
#pragma unroll
        for (int nn = 0; nn < 4; ++nn) {
            half8 bf = *(const half8*)(bbuf + bbyte0 + nn * 1024);
            acc[0][nn] = MFMA16(a0, bf, acc[0][nn]);
            acc[1][nn] = MFMA16(a1, bf, acc[1][nn]);
        }
        __syncthreads();   // DMA done (vmcnt) + all reads of bufs done (lgkm)
    }

    // ---- scores + per-wave argmin. C layout: col=lane&31,
    //      row=(reg&3)+8*(reg>>2)+4*(lane>>5)  (verified rounds 5-10) ----
    {
        const int h = l >> 5;
#pragma unroll
        for (int mm = 0; mm < 2; ++mm) {
#pragma unroll
            for (int rg = 0; rg < 16; ++rg) {
                const int row = mm * 32 + (rg & 3) + 8 * (rg >> 2) + 4 * h;
                const float znv = zn_s[row];
                float bv = 3.0e38f; int bi = 0;
#pragma unroll
                for (int nn = 0; nn < 4; ++nn) {
                    const int col = w * 128 + nn * 32 + ln;
                    float k1 = znv + en_s[col];
                    float sc = k1 - acc[mm][nn][rg] * (2.0f / ESCALE);
                    if (sc < bv) { bv = sc; bi = col; }
                }
#pragma unroll
                for (int off = 1; off < 32; off <<= 1) {
                    float ov = __shfl_xor(bv, off, 64);
                    int   oi = __shfl_xor(bi, off, 64);
                    if (ov < bv || (ov == bv && oi < bi)) { bv = ov; bi = oi; }
                }
                if (ln == 0) {
                    redv[w * MT + row] = bv;
                    redi[w * MT + row] = bi;
                }
            }
        }
    }
    __syncthreads();

    // ---- final argmin (w ascending = col ascending); index/count; loss ----
    if (t < MT) {
        float bv = redv[t]; int bi = redi[t];
#pragma unroll
        for (int s = 1; s < 8; ++s) {
            float ov = redv[s * MT + t]; int oi = redi[s * MT + t];
            if (ov < bv || (ov == bv && oi < bi)) { bv = ov; bi = oi; }
        }
        out_idx[n0 + t] = (float)bi;
        atomicAdd(&counts[bi], 1.0f);
        float lsum = bv;
#pragma unroll
        for (int off = 32; off > 0; off >>= 1) lsum += __shfl_down(lsum, off, 64);
        if ((t & 63) == 0) atomicAdd(loss_acc, lsum);
    }
#undef STAGEB
}

// ---------------- epilogue: z_q gather-write only (no z read, no loss) ----------------
__global__ __launch_bounds__(256) void vq_epi(const float* __restrict__ embed,
                                              const float* __restrict__ out_idx,
                                              float* __restrict__ out_zq) {
    const int n = blockIdx.x * 256 + threadIdx.x;
    const int b = n >> 13, s = n & 8191;
    const int idx = (int)out_idx[n];
    const float4* er = reinterpret_cast<const float4*>(embed + (size_t)idx * Cdim);
    float* oq = out_zq + (size_t)b * ((size_t)Cdim * Ssp) + s;
#pragma unroll 4
    for (int c4 = 0; c4 < Cdim / 4; ++c4) {
        float4 e = er[c4];                   // per-lane gather, L2-hot (embed = 1MB)
        const int c = c4 * 4;
        __builtin_nontemporal_store(e.x, oq + (size_t)(c + 0) * Ssp);
        __builtin_nontemporal_store(e.y, oq + (size_t)(c + 1) * Ssp);
        __builtin_nontemporal_store(e.z, oq + (size_t)(c + 2) * Ssp);
        __builtin_nontemporal_store(e.w, oq + (size_t)(c + 3) * Ssp);
    }
}

// ================= fallback (round-4 verified kernel, used if ws too small) =================
#define PTS 64
#define CT  128
#define KC  32
__global__ __launch_bounds__(256, 2) void vq_main_fb(const float* __restrict__ z,
                                                     const float* __restrict__ embed,
                                                     const float* __restrict__ enorm,
                                                     float* __restrict__ out_zq,
                                                     float* __restrict__ out_idx,
                                                     float* __restrict__ loss_acc,
                                                     float* __restrict__ counts) {
    __shared__ __attribute__((aligned(16))) float smem[Cdim * PTS + KC * CT];
    float* zt = smem;
    float* et = smem + Cdim * PTS;
    const int t  = threadIdx.x;
    const int n0 = blockIdx.x * PTS;
    const int b  = n0 >> 13;
    const int s0 = n0 & 8191;
    const float* zb = z + (size_t)b * Cdim * Ssp + s0;
    {
        const int p4 = (t & 15) * 4, crow = t >> 4;
#pragma unroll
        for (int it = 0; it < 16; ++it) {
            int c = it * 16 + crow;
            float4 v = *reinterpret_cast<const float4*>(zb + (size_t)c * Ssp + p4);
            *reinterpret_cast<float4*>(&zt[c * PTS + p4]) = v;
        }
    }
    __syncthreads();
    {
        const int p = t & 63, qq = t >> 6;
        float sacc = 0.f;
#pragma unroll 8
        for (int c = qq * 64; c < qq * 64 + 64; ++c) { float v = zt[c * PTS + p]; sacc += v * v; }
        et[qq * 64 + p] = sacc;
    }
    __syncthreads();
    const int pg = t & 15, jg = t >> 4;
    const int p0 = pg * 4;
    float zn[4];
#pragma unroll
    for (int i = 0; i < 4; ++i) {
        int p = p0 + i;
        zn[i] = ((et[p] + et[64 + p]) + et[128 + p]) + et[192 + p];
    }
    float bestv[4] = {3.0e38f, 3.0e38f, 3.0e38f, 3.0e38f};
    int   besti[4] = {0, 0, 0, 0};
    const int dj = t >> 3, q = t & 7;
    const int sw_st = (q & 3) << 3;
    for (int jt = 0; jt < NCODES / CT; ++jt) {
        const int J0 = jt * CT;
        float acc[4][8];
#pragma unroll
        for (int i = 0; i < 4; ++i)
#pragma unroll
            for (int m = 0; m < 8; ++m) acc[i][m] = 0.f;
        for (int ks = 0; ks < Cdim / KC; ++ks) {
            const int cc0 = ks * KC;
            __syncthreads();
#pragma unroll
            for (int i = 0; i < 4; ++i) {
                const int jrel = dj + 32 * i;
                const float4 v = *reinterpret_cast<const float4*>(
                    embed + (size_t)(J0 + jrel) * Cdim + cc0 + q * 4);
                const int c0 = q * 4;
                const int jsw = jrel ^ sw_st;
                et[(c0 + 0) * CT + jsw] = v.x;
                et[(c0 + 1) * CT + jsw] = v.y;
                et[(c0 + 2) * CT + jsw] = v.z;
                et[(c0 + 3) * CT + jsw] = v.w;
            }
            __syncthreads();
#pragma unroll 4
            for (int c = 0; c < KC; ++c) {
                const float4 zp = *reinterpret_cast<const float4*>(&zt[(cc0 + c) * PTS + p0]);
                const int jb = (jg * 8) ^ (((c >> 2) & 3) << 3);
                const float4 ea = *reinterpret_cast<const float4*>(&et[c * CT + jb]);
                const float4 eb = *reinterpret_cast<const float4*>(&et[c * CT + jb + 4]);
                const float zc[4] = {zp.x, zp.y, zp.z, zp.w};
                const float ec[8] = {ea.x, ea.y, ea.z, ea.w, eb.x, eb.y, eb.z, eb.w};
#pragma unroll
                for (int i = 0; i < 4; ++i)
#pragma unroll
                    for (int m = 0; m < 8; ++m) acc[i][m] += zc[i] * ec[m];
            }
        }
#pragma unroll
        for (int m = 0; m < 8; ++m) {
            const int cid = J0 + jg * 8 + m;
            const float en = enorm[cid];
#pragma unroll
            for (int i = 0; i < 4; ++i) {
                float k1 = zn[i] + en;
                float sc = k1 - 2.0f * acc[i][m];
                if (sc < bestv[i]) { bestv[i] = sc; besti[i] = cid; }
            }
        }
    }
    __syncthreads();
    float* rv = et; int* ri = (int*)(et + 1024); int* idxf = (int*)(et + 2048);
#pragma unroll
    for (int i = 0; i < 4; ++i) { int p = p0 + i; rv[p * 16 + jg] = bestv[i]; ri[p * 16 + jg] = besti[i]; }
    __syncthreads();
    if (t < PTS) {
        int p = t;
        float bv = rv[p * 16]; int bi = ri[p * 16];
        for (int g = 1; g < 16; ++g) {
            float v = rv[p * 16 + g]; int ii = ri[p * 16 + g];
            if (v < bv || (v == bv && ii < bi)) { bv = v; bi = ii; }
        }
        idxf[p] = bi;
        out_idx[n0 + p] = (float)bi;
        atomicAdd(&counts[bi], 1.0f);
    }
    __syncthreads();
    float lsum = 0.f;
    {
        const int p = t & 63, cbase = t >> 6;
        const int myidx = idxf[p];
        const float4* erow4 = reinterpret_cast<const float4*>(embed + (size_t)myidx * Cdim);
        float* ob = out_zq + (size_t)b * Cdim * Ssp + s0 + p;
#pragma unroll 4
        for (int pass = 0; pass < 16; ++pass) {
            int c = cbase * 64 + pass * 4;
            float4 e = erow4[c >> 2];
            ob[(size_t)(c + 0) * Ssp] = e.x;
            ob[(size_t)(c + 1) * Ssp] = e.y;
            ob[(size_t)(c + 2) * Ssp] = e.z;
            ob[(size_t)(c + 3) * Ssp] = e.w;
            float d0 = zt[(c + 0) * PTS + p] - e.x;
            float d1 = zt[(c + 1) * PTS + p] - e.y;
            float d2 = zt[(c + 2) * PTS + p] - e.z;
            float d3 = zt[(c + 3) * PTS + p] - e.w;
            lsum += d0 * d0 + d1 * d1 + d2 * d2 + d3 * d3;
        }
    }
#pragma unroll
    for (int off = 32; off > 0; off >>= 1) lsum += __shfl_down(lsum, off, 64);
    if ((t & 63) == 0) atomicAdd(loss_acc, lsum);
}

// ---------------- finalize ----------------
__global__ __launch_bounds__(1024) void vq_final(const float* __restrict__ counts,
                                                 const float* __restrict__ loss_acc,
                                                 float* __restrict__ out_loss,
                                                 float* __restrict__ out_perp) {
    __shared__ float red[16];
    int t = threadIdx.x;
    float cnt = counts[t];
    float avg = cnt * (1.0f / (float)Npts);
    float term = avg * logf(avg + 1e-10f);
#pragma unroll
    for (int off = 32; off > 0; off >>= 1) term += __shfl_down(term, off, 64);
    if ((t & 63) == 0) red[t >> 6] = term;
    __syncthreads();
    if (t == 0) {
        float s = 0.f;
        for (int i = 0; i < 16; ++i) s += red[i];
        *out_perp = expf(-s);
        *out_loss = BETA * loss_acc[0] * (1.0f / 16777216.0f);
    }
}

extern "C" void kernel_launch(void* const* d_in, const int* in_sizes, int n_in,
                              void* d_out, int out_size, void* d_ws, size_t ws_size,
                              hipStream_t stream) {
    const float* z     = (const float*)d_in[0];
    const float* embed = (const float*)d_in[1];

    float* ws       = (float*)d_ws;
    float* loss_acc = ws;            // [0]
    float* counts   = ws + 64;       // [1024]
    float* enorm    = ws + 2048;     // [1024]

    float* out_zq   = (float*)d_out;
    float* out_idx  = out_zq + (size_t)Npts * Cdim;
    float* out_loss = out_idx + Npts;
    float* out_perp = out_loss + 1;

    hipMemsetAsync(d_ws, 0, 2048 * sizeof(float), stream);
    enorm_kernel<<<NCODES / 256, 256, 0, stream>>>(embed, enorm);

    if (ws_size >= WS_NEED) {
        f16* Bws = (f16*)((char*)d_ws + 65536);
        prep_kernel<<<768, 256, 0, stream>>>(embed, Bws);
        vq_gemm<<<Npts / MT, 512, 0, stream>>>(z, Bws, enorm, out_idx,
                                               loss_acc, counts);
        vq_epi<<<Npts / 256, 256, 0, stream>>>(embed, out_idx, out_zq);
    } else {
        vq_main_fb<<<Npts / PTS, 256, 0, stream>>>(z, embed, enorm, out_zq, out_idx,
                                                   loss_acc, counts);
    }
    vq_final<<<1, 1024, 0, stream>>>(counts, loss_acc, out_loss, out_perp);
}

// Round 12
// 200.705 us; speedup vs baseline: 7.4788x; 1.2271x over previous
//
#include <hip/hip_runtime.h>
#include <math.h>

#define Cdim   256
#define Ssp    8192      // D*H*W
#define Npts   65536
#define NCODES 1024
#define BETA   0.25f
#define MT     128       // points per GEMM block
#define NKC    48        // K-chunks of 16 (K=768 split: [zh|zh|zl] x [eh|el|eh])
#define ESCALE 8192.0f   // keep el out of f16-subnormal truncation
#define WS_NEED (65536 + (size_t)786432 * 2)

typedef _Float16 f16;
typedef f16   half8  __attribute__((ext_vector_type(8)));
typedef float f32x16 __attribute__((ext_vector_type(16)));

#define MFMA16(A, B, C) __builtin_amdgcn_mfma_f32_32x32x16_f16(A, B, C, 0, 0, 0)

// ---------------- embed norms ----------------
__global__ __launch_bounds__(256) void enorm_kernel(const float* __restrict__ embed,
                                                    float* __restrict__ enorm) {
    int j = blockIdx.x * 256 + threadIdx.x;
    if (j >= NCODES) return;
    const float4* row = reinterpret_cast<const float4*>(embed + (size_t)j * Cdim);
    float s = 0.f;
#pragma unroll 8
    for (int c4 = 0; c4 < Cdim / 4; ++c4) {
        float4 v = row[c4];
        s += v.x * v.x + v.y * v.y + v.z * v.z + v.w * v.w;
    }
    enorm[j] = s;
}

// ---------------- prep: split embed into f16 hi/lo, chunk-tiled ----------------
// Bws: [kc=48][code=1024][k'=16] f16. k = kc*16+k'; k 0..255 -> eh, 256..511 -> el,
// 512..767 -> eh. Scaled by ESCALE. (verified rounds 5-11)
__global__ __launch_bounds__(256) void prep_kernel(const float* __restrict__ embed,
                                                   f16* __restrict__ Bws) {
    int tid = blockIdx.x * 256 + threadIdx.x;
    int o4 = tid * 4;
    int kc = o4 >> 14;
    int r  = o4 & 16383;
    int j  = r >> 4;
    int k0 = r & 15;
#pragma unroll
    for (int i = 0; i < 4; ++i) {
        int k = kc * 16 + k0 + i;
        int c = k & 255;
        float ev = embed[j * 256 + c] * ESCALE;
        f16 eh = (f16)ev;
        f16 v  = (k >= 256 && k < 512) ? (f16)(ev - (float)eh) : eh;
        Bws[o4 + i] = v;
    }
}

// granule id (region boundaries 16/32 verified rounds 5-11)
#define GG(k) (((k) < 16) ? (2 * (k) + kb) : ((k) < 32) ? (2 * ((k) - 16) + kb) \
                                                        : (32 + 2 * ((k) - 32) + kb))

// ---------------- MFMA GEMM + fused argmin + loss (v8: pinned pipeline) ----------------
// r9 structure (512 thr / 8 waves = 2m x 4n, MT=128, 2 jh halves, A in 128KB LDS,
// B global->reg) with the K-loop rewritten as a 2x ping-pong where each half-iter is:
//   {load next chunk A(ds_read)+B(global)}  -> sched_barrier(0)
//   setprio(1) + 8 MFMAs + setprio(0)       -> sched_barrier(0)
// The fences PIN load-issue before the MFMA cluster so the compiler's minimal
// waitcnt for the current B group is a counted vmcnt (full chunk in flight),
// not an effective drain (it was free to sink prefetches below the MFMAs).
__global__ __launch_bounds__(512, 2) void vq_gemm(const float* __restrict__ z,
                                                  const f16* __restrict__ Bws,
                                                  const float* __restrict__ enorm,
                                                  float* __restrict__ out_idx,
                                                  float* __restrict__ loss_acc,
                                                  float* __restrict__ counts) {
    __shared__ __attribute__((aligned(16))) f16 As[MT * 512];   // 128 KB
    __shared__ float en_s[NCODES];                              // 4 KB
    __shared__ float znp[4 * MT];                               // 2 KB
    __shared__ float zn_s[MT];                                  // 0.5 KB
    __shared__ float redv[8 * MT];                              // 4 KB (jh,wn) x row
    __shared__ int   redi[8 * MT];                              // 4 KB

    const int t  = threadIdx.x;
    const int l  = t & 63;
    const int w  = t >> 6;            // 0..7
    const int wm = w >> 2;            // 0..1 : rows [wm*64, +64)
    const int wn = w & 3;             // 0..3 : codes [wn*128, +128) per half
    const int ln = l & 31;
    const int kb = l >> 5;
    const int n0 = blockIdx.x * MT;
    const int b  = n0 >> 13;
    const int s0 = n0 & 8191;

    // ---- stage A (zh granules 0..31, zl 32..63, swizzle g^=(p&7)) ----
    {
        const int p = t & 127;        // point row
        const int q = t >> 7;         // c-quad, 64 c each (same 64-c tree as r2/r6)
        const float* zb = z + (size_t)b * ((size_t)Cdim * Ssp) + s0;
        float zsq = 0.f;
#pragma unroll
        for (int gi = 0; gi < 8; ++gi) {
            const int c0 = q * 64 + gi * 8;
            half8 hh, ll;
#pragma unroll
            for (int u = 0; u < 8; ++u) {     // c ascending -> zsq order == rounds 2/5-11
                float zv = zb[(size_t)(c0 + u) * Ssp + p];
                zsq += zv * zv;
                f16 zh = (f16)zv;
                hh[u] = zh;
                ll[u] = (f16)(zv - (float)zh);
            }
            const int g0 = c0 >> 3;           // 0..31
            *(half8*)&As[p * 512 + 8 * (g0 ^ (p & 7))]        = hh;
            *(half8*)&As[p * 512 + 8 * ((32 + g0) ^ (p & 7))] = ll;
        }
        znp[q * MT + p] = zsq;
    }
    for (int i = t; i < NCODES; i += 512) en_s[i] = enorm[i];
    __syncthreads();
    if (t < MT)
        zn_s[t] = ((znp[t] + znp[MT + t]) + znp[2 * MT + t]) + znp[3 * MT + t];
    __syncthreads();

    const int rowA = wm * 64 + ln;

    // load group macros: A frags from LDS + B frags from global for chunk kcv
#define LOADG(kcv, A0, A1, B0, B1, B2, B3)                               \
    {                                                                    \
        const int ggx  = GG(kcv);                                        \
        const int gswx = 8 * (ggx ^ (ln & 7));                           \
        A0 = *(const half8*)&As[rowA * 512 + gswx];                      \
        A1 = *(const half8*)&As[(rowA + 32) * 512 + gswx];               \
        const f16* srcx = bbase + (size_t)(kcv) * 16384;                 \
        B0 = *(const half8*)(srcx);                                      \
        B1 = *(const half8*)(srcx + 512);                                \
        B2 = *(const half8*)(srcx + 1024);                               \
        B3 = *(const half8*)(srcx + 1536);                               \
    }

#define MFMAG(A0, A1, B0, B1, B2, B3)                                    \
    __builtin_amdgcn_s_setprio(1);                                       \
    acc[0][0] = MFMA16(A0, B0, acc[0][0]);                               \
    acc[1][0] = MFMA16(A1, B0, acc[1][0]);                               \
    acc[0][1] = MFMA16(A0, B1, acc[0][1]);                               \
    acc[1][1] = MFMA16(A1, B1, acc[1][1]);                               \
    acc[0][2] = MFMA16(A0, B2, acc[0][2]);                               \
    acc[1][2] = MFMA16(A1, B2, acc[1][2]);                               \
    acc[0][3] = MFMA16(A0, B3, acc[0][3]);                               \
    acc[1][3] = MFMA16(A1, B3, acc[1][3]);                               \
    __builtin_amdgcn_s_setprio(0);

    // ---- two code-halves of 512; wave (wm,wn) owns rows [wm*64,+64) x codes
    //      [jh*512+wn*128, +128) ----
#pragma unroll 1
    for (int jh = 0; jh < 2; ++jh) {
        f32x16 acc[2][4] = {};
        const f16* bbase = Bws + (size_t)(jh * 512 + wn * 128 + ln) * 16 + kb * 8;

        half8 aA0, aA1, bA0, bA1, bA2, bA3;   // even chunks
        half8 aB0, aB1, bB0, bB1, bB2, bB3;   // odd chunks
        LOADG(0, aA0, aA1, bA0, bA1, bA2, bA3)

#pragma unroll 1
        for (int kc = 0; kc < NKC; kc += 2) {
            // issue loads for kc+1, pinned before the MFMA cluster on chunk kc
            LOADG(kc + 1, aB0, aB1, bB0, bB1, bB2, bB3)
            __builtin_amdgcn_sched_barrier(0);
            MFMAG(aA0, aA1, bA0, bA1, bA2, bA3)
            __builtin_amdgcn_sched_barrier(0);

            // issue loads for kc+2 (clamped; dead on last iter), then MFMA kc+1
            const int kc2 = (kc + 2 < NKC) ? kc + 2 : NKC - 1;
            LOADG(kc2, aA0, aA1, bA0, bA1, bA2, bA3)
            __builtin_amdgcn_sched_barrier(0);
            MFMAG(aB0, aB1, bB0, bB1, bB2, bB3)
            __builtin_amdgcn_sched_barrier(0);
        }

        // ---- scores + per-half argmin. C layout: col=lane&31,
        //      row=(reg&3)+8*(reg>>2)+4*(lane>>5)  (verified rounds 5-11) ----
        const int h = l >> 5;
#pragma unroll
        for (int mm = 0; mm < 2; ++mm) {
#pragma unroll
            for (int rg = 0; rg < 16; ++rg) {
                const int row = wm * 64 + mm * 32 + (rg & 3) + 8 * (rg >> 2) + 4 * h;
                const float znv = zn_s[row];
                float bv = 3.0e38f; int bi = 0;
#pragma unroll
                for (int nn = 0; nn < 4; ++nn) {
                    const int col = jh * 512 + wn * 128 + nn * 32 + ln;
                    float k1 = znv + en_s[col];
                    float sc = k1 - acc[mm][nn][rg] * (2.0f / ESCALE);
                    if (sc < bv) { bv = sc; bi = col; }
                }
#pragma unroll
                for (int off = 1; off < 32; off <<= 1) {
                    float ov = __shfl_xor(bv, off, 64);
                    int   oi = __shfl_xor(bi, off, 64);
                    if (ov < bv || (ov == bv && oi < bi)) { bv = ov; bi = oi; }
                }
                if (ln == 0) {
                    redv[(jh * 4 + wn) * MT + row] = bv;
                    redi[(jh * 4 + wn) * MT + row] = bi;
                }
            }
        }
    }
    __syncthreads();

    // ---- final argmin; index/count; loss = sum of best scores ----
    if (t < MT) {
        float bv = redv[t]; int bi = redi[t];
#pragma unroll
        for (int s = 1; s < 8; ++s) {
            float ov = redv[s * MT + t]; int oi = redi[s * MT + t];
            if (ov < bv || (ov == bv && oi < bi)) { bv = ov; bi = oi; }
        }
        out_idx[n0 + t] = (float)bi;
        atomicAdd(&counts[bi], 1.0f);
        float lsum = bv;
#pragma unroll
        for (int off = 32; off > 0; off >>= 1) lsum += __shfl_down(lsum, off, 64);
        if ((t & 63) == 0) atomicAdd(loss_acc, lsum);
    }
#undef LOADG
#undef MFMAG
}

// ---------------- epilogue: z_q gather-write only (no z read, no loss) ----------------
__global__ __launch_bounds__(256) void vq_epi(const float* __restrict__ embed,
                                              const float* __restrict__ out_idx,
                                              float* __restrict__ out_zq) {
    const int n = blockIdx.x * 256 + threadIdx.x;
    const int b = n >> 13, s = n & 8191;
    const int idx = (int)out_idx[n];
    const float4* er = reinterpret_cast<const float4*>(embed + (size_t)idx * Cdim);
    float* oq = out_zq + (size_t)b * ((size_t)Cdim * Ssp) + s;
#pragma unroll 4
    for (int c4 = 0; c4 < Cdim / 4; ++c4) {
        float4 e = er[c4];                   // per-lane gather, L2-hot (embed = 1MB)
        const int c = c4 * 4;
        __builtin_nontemporal_store(e.x, oq + (size_t)(c + 0) * Ssp);
        __builtin_nontemporal_store(e.y, oq + (size_t)(c + 1) * Ssp);
        __builtin_nontemporal_store(e.z, oq + (size_t)(c + 2) * Ssp);
        __builtin_nontemporal_store(e.w, oq + (size_t)(c + 3) * Ssp);
    }
}

// ================= fallback (round-4 verified kernel, used if ws too small) =================
#define PTS 64
#define CT  128
#define KC  32
__global__ __launch_bounds__(256, 2) void vq_main_fb(const float* __restrict__ z,
                                                     const float* __restrict__ embed,
                                                     const float* __restrict__ enorm,
                                                     float* __restrict__ out_zq,
                                                     float* __restrict__ out_idx,
                                                     float* __restrict__ loss_acc,
                                                     float* __restrict__ counts) {
    __shared__ __attribute__((aligned(16))) float smem[Cdim * PTS + KC * CT];
    float* zt = smem;
    float* et = smem + Cdim * PTS;
    const int t  = threadIdx.x;
    const int n0 = blockIdx.x * PTS;
    const int b  = n0 >> 13;
    const int s0 = n0 & 8191;
    const float* zb = z + (size_t)b * Cdim * Ssp + s0;
    {
        const int p4 = (t & 15) * 4, crow = t >> 4;
#pragma unroll
        for (int it = 0; it < 16; ++it) {
            int c = it * 16 + crow;
            float4 v = *reinterpret_cast<const float4*>(zb + (size_t)c * Ssp + p4);
            *reinterpret_cast<float4*>(&zt[c * PTS + p4]) = v;
        }
    }
    __syncthreads();
    {
        const int p = t & 63, qq = t >> 6;
        float sacc = 0.f;
#pragma unroll 8
        for (int c = qq * 64; c < qq * 64 + 64; ++c) { float v = zt[c * PTS + p]; sacc += v * v; }
        et[qq * 64 + p] = sacc;
    }
    __syncthreads();
    const int pg = t & 15, jg = t >> 4;
    const int p0 = pg * 4;
    float zn[4];
#pragma unroll
    for (int i = 0; i < 4; ++i) {
        int p = p0 + i;
        zn[i] = ((et[p] + et[64 + p]) + et[128 + p]) + et[192 + p];
    }
    float bestv[4] = {3.0e38f, 3.0e38f, 3.0e38f, 3.0e38f};
    int   besti[4] = {0, 0, 0, 0};
    const int dj = t >> 3, q = t & 7;
    const int sw_st = (q & 3) << 3;
    for (int jt = 0; jt < NCODES / CT; ++jt) {
        const int J0 = jt * CT;
        float acc[4][8];
#pragma unroll
        for (int i = 0; i < 4; ++i)
#pragma unroll
            for (int m = 0; m < 8; ++m) acc[i][m] = 0.f;
        for (int ks = 0; ks < Cdim / KC; ++ks) {
            const int cc0 = ks * KC;
            __syncthreads();
#pragma unroll
            for (int i = 0; i < 4; ++i) {
                const int jrel = dj + 32 * i;
                const float4 v = *reinterpret_cast<const float4*>(
                    embed + (size_t)(J0 + jrel) * Cdim + cc0 + q * 4);
                const int c0 = q * 4;
                const int jsw = jrel ^ sw_st;
                et[(c0 + 0) * CT + jsw] = v.x;
                et[(c0 + 1) * CT + jsw] = v.y;
                et[(c0 + 2) * CT + jsw] = v.z;
                et[(c0 + 3) * CT + jsw] = v.w;
            }
            __syncthreads();
#pragma unroll 4
            for (int c = 0; c < KC; ++c) {
                const float4 zp = *reinterpret_cast<const float4*>(&zt[(cc0 + c) * PTS + p0]);
                const int jb = (jg * 8) ^ (((c >> 2) & 3) << 3);
                const float4 ea = *reinterpret_cast<const float4*>(&et[c * CT + jb]);
                const float4 eb = *reinterpret_cast<const float4*>(&et[c * CT + jb + 4]);
                const float zc[4] = {zp.x, zp.y, zp.z, zp.w};
                const float ec[8] = {ea.x, ea.y, ea.z, ea.w, eb.x, eb.y, eb.z, eb.w};
#pragma unroll
                for (int i = 0; i < 4; ++i)
#pragma unroll
                    for (int m = 0; m < 8; ++m) acc[i][m] += zc[i] * ec[m];
            }
        }
#pragma unroll
        for (int m = 0; m < 8; ++m) {
            const int cid = J0 + jg * 8 + m;
            const float en = enorm[cid];
#pragma unroll
            for (int i = 0; i < 4; ++i) {
                float k1 = zn[i] + en;
                float sc = k1 - 2.0f * acc[i][m];
                if (sc < bestv[i]) { bestv[i] = sc; besti[i] = cid; }
            }
        }
    }
    __syncthreads();
    float* rv = et; int* ri = (int*)(et + 1024); int* idxf = (int*)(et + 2048);
#pragma unroll
    for (int i = 0; i < 4; ++i) { int p = p0 + i; rv[p * 16 + jg] = bestv[i]; ri[p * 16 + jg] = besti[i]; }
    __syncthreads();
    if (t < PTS) {
        int p = t;
        float bv = rv[p * 16]; int bi = ri[p * 16];
        for (int g = 1; g < 16; ++g) {
            float v = rv[p * 16 + g]; int ii = ri[p * 16 + g];
            if (v < bv || (v == bv && ii < bi)) { bv = v; bi = ii; }
        }
        idxf[p] = bi;
        out_idx[n0 + p] = (float)bi;
        atomicAdd(&counts[bi], 1.0f);
    }
    __syncthreads();
    float lsum = 0.f;
    {
        const int p = t & 63, cbase = t >> 6;
        const int myidx = idxf[p];
        const float4* erow4 = reinterpret_cast<const float4*>(embed + (size_t)myidx * Cdim);
        float* ob = out_zq + (size_t)b * Cdim * Ssp + s0 + p;
#pragma unroll 4
        for (int pass = 0; pass < 16; ++pass) {
            int c = cbase * 64 + pass * 4;
            float4 e = erow4[c >> 2];
            ob[(size_t)(c + 0) * Ssp] = e.x;
            ob[(size_t)(c + 1) * Ssp] = e.y;
            ob[(size_t)(c + 2) * Ssp] = e.z;
            ob[(size_t)(c + 3) * Ssp] = e.w;
            float d0 = zt[(c + 0) * PTS + p] - e.x;
            float d1 = zt[(c + 1) * PTS + p] - e.y;
            float d2 = zt[(c + 2) * PTS + p] - e.z;
            float d3 = zt[(c + 3) * PTS + p] - e.w;
            lsum += d0 * d0 + d1 * d1 + d2 * d2 + d3 * d3;
        }
    }
#pragma unroll
    for (int off = 32; off > 0; off >>= 1) lsum += __shfl_down(lsum, off, 64);
    if ((t & 63) == 0) atomicAdd(loss_acc, lsum);
}

// ---------------- finalize ----------------
__global__ __launch_bounds__(1024) void vq_final(const float* __restrict__ counts,
                                                 const float* __restrict__ loss_acc,
                                                 float* __restrict__ out_loss,
                                                 float* __restrict__ out_perp) {
    __shared__ float red[16];
    int t = threadIdx.x;
    float cnt = counts[t];
    float avg = cnt * (1.0f / (float)Npts);
    float term = avg * logf(avg + 1e-10f);
#pragma unroll
    for (int off = 32; off > 0; off >>= 1) term += __shfl_down(term, off, 64);
    if ((t & 63) == 0) red[t >> 6] = term;
    __syncthreads();
    if (t == 0) {
        float s = 0.f;
        for (int i = 0; i < 16; ++i) s += red[i];
        *out_perp = expf(-s);
        *out_loss = BETA * loss_acc[0] * (1.0f / 16777216.0f);
    }
}

extern "C" void kernel_launch(void* const* d_in, const int* in_sizes, int n_in,
                              void* d_out, int out_size, void* d_ws, size_t ws_size,
                              hipStream_t stream) {
    const float* z     = (const float*)d_in[0];
    const float* embed = (const float*)d_in[1];

    float* ws       = (float*)d_ws;
    float* loss_acc = ws;            // [0]
    float* counts   = ws + 64;       // [1024]
    float* enorm    = ws + 2048;     // [1024]

    float* out_zq   = (float*)d_out;
    float* out_idx  = out_zq + (size_t)Npts * Cdim;
    float* out_loss = out_idx + Npts;
    float* out_perp = out_loss + 1;

    hipMemsetAsync(d_ws, 0, 2048 * sizeof(float), stream);
    enorm_kernel<<<NCODES / 256, 256, 0, stream>>>(embed, enorm);

    if (ws_size >= WS_NEED) {
        f16* Bws = (f16*)((char*)d_ws + 65536);
        prep_kernel<<<768, 256, 0, stream>>>(embed, Bws);
        vq_gemm<<<Npts / MT, 512, 0, stream>>>(z, Bws, enorm, out_idx,
                                               loss_acc, counts);
        vq_epi<<<Npts / 256, 256, 0, stream>>>(embed, out_idx, out_zq);
    } else {
        vq_main_fb<<<Npts / PTS, 256, 0, stream>>>(z, embed, enorm, out_zq, out_idx,
                                                   loss_acc, counts);
    }
    vq_final<<<1, 1024, 0, stream>>>(counts, loss_acc, out_loss, out_perp);
}